// Round 9
// baseline (205.781 us; speedup 1.0000x reference)
//
#include <hip/hip_runtime.h>
#include <cstdint>

#define E_EDGES 400000
#define N_NODES 25000
#define NG      25000          // groups of 16 edges
#define NPACK   18432          // ushorts: 17 K-tiles (17408) + 2 W1^T A-frags (1024)
#define EBLOCKS 1024           // exactly 4 blocks/CU (34.8KB LDS each)
#define ESTRIDE (EBLOCKS*4)    // 4096 waves, grid-stride over groups

typedef float  f32x4  __attribute__((ext_vector_type(4)));
typedef __bf16 bf16x8 __attribute__((ext_vector_type(8)));

static __device__ __forceinline__ ushort f2bf(float f) {
    union { __bf16 b; ushort u; } c; c.b = (__bf16)f; return c.u;
}

// ---------------------------------------------------------------------------
// K_pack: W2(+b2 17th tile) -> MFMA frag order with kap remap; W1^T A-frags.
// kap(kg,j) = j<4 ? 4kg+j : 16+4kg+(j-4)   (matches h-MFMA C layout)
// Layout [kt:17][nt:2][kg:4][ln:16][j:8]; used as FIRST mfma operand now
// (A[row=ln -> o'][k=kg*8+j]) -- same bytes as the old B-frag role.
// ---------------------------------------------------------------------------
__global__ void __launch_bounds__(256) k_pack(const float* __restrict__ W2,
                                              const float* __restrict__ b2,
                                              const float* __restrict__ W1,
                                              ushort* __restrict__ packed) {
    int t = blockIdx.x * 256 + threadIdx.x;
    if (t >= NPACK) return;
    float v = 0.0f;
    if (t < 17408) {
        int j  = t & 7;
        int ln = (t >> 3) & 15;
        int kg = (t >> 7) & 3;
        int nt = (t >> 9) & 1;
        int kt = t >> 10;
        int kap = (j < 4) ? (kg * 4 + j) : (16 + kg * 4 + (j - 4));
        if (kt < 16)       v = W2[kap * 512 + kt * 32 + nt * 16 + ln];
        else if (kap < 16) v = b2[kap * 32 + nt * 16 + ln];
    } else {
        int idx  = t - 17408;
        int half = idx >> 9;
        int lane = (idx >> 3) & 63;
        int j    = idx & 7;
        int kg = lane >> 4, ln = lane & 15;
        if (kg == 0) v = W1[j * 32 + half * 16 + ln];  // A[m=ln(+16*half)][k=j]
    }
    packed[t] = f2bf(v);
}

// ---------------------------------------------------------------------------
// K_edge: swapped-operand MFMA -> lane owns its own edge's outputs:
//   acc = mfma(W2frag, a_built, acc); C[row=o'=kg*4+r][col=edge=ln]
//   -> scatter = 8 atomics per lane to agg[dst(ln)*32 + (nt*16+kg*4+r)],
//      no LDS transpose, no tbuf, no bank conflicts.
// Two-level pipeline (ei 2 bodies ahead, ea/x 1 body ahead). cnt inline.
// ---------------------------------------------------------------------------
__global__ void __launch_bounds__(256) k_edge(const float* __restrict__ ea,
                                              const float* __restrict__ x,
                                              const int* __restrict__ ei,
                                              const ushort* __restrict__ packed,
                                              const float* __restrict__ b1,
                                              float* __restrict__ agg,
                                              uint* __restrict__ cnt_u) {
    __shared__ alignas(16) ushort w2l[17408];
    {
        const uint4* s = (const uint4*)packed;
        uint4* d = (uint4*)w2l;
        for (int i = threadIdx.x; i < 2176; i += 256) d[i] = s[i];
    }
    __syncthreads();

    const int lane = threadIdx.x & 63;
    const int ln = lane & 15;
    const int kg = lane >> 4;
    const int wid = blockIdx.x * 4 + (threadIdx.x >> 6);

    // loop-invariant register state
    const bf16x8 aw0 = *(const bf16x8*)(packed + 17408 + (size_t)lane * 8);
    const bf16x8 aw1 = *(const bf16x8*)(packed + 17408 + 512 + (size_t)lane * 8);
    const f32x4 blo4 = *(const f32x4*)(b1 + 4 * kg);
    const f32x4 bhi4 = *(const f32x4*)(b1 + 16 + 4 * kg);

    const f32x4 z4 = {0.f, 0.f, 0.f, 0.f};
    const __bf16 zb = (__bf16)0.0f;

    // ---- pipeline state
    int g = wid;                            // wid < 4096 <= NG
    f32x4 eac0, eac1, xc0, xc1, xc2, xc3;
    int s_nx = 0;
    {
        const int s0 = ei[g * 16 + ln];
        const f32x4* ep = (const f32x4*)(ea + (size_t)(g * 16 + ln) * 8);
        eac0 = ep[0]; eac1 = ep[1];
        const f32x4* xp = (const f32x4*)(x + (size_t)s0 * 16);
        xc0 = xp[0]; xc1 = xp[1]; xc2 = xp[2]; xc3 = xp[3];
        const int g1 = g + ESTRIDE;
        if (g1 < NG) s_nx = ei[g1 * 16 + ln];
    }

    while (true) {
        const int gn = g + ESTRIDE;
        const bool pf = gn < NG;
        const int g16 = g * 16;

        // ---- issue next body's ea + x, and ei two bodies ahead
        f32x4 ean0 = z4, ean1 = z4, xn0 = z4, xn1 = z4, xn2 = z4, xn3 = z4;
        int s_nx2 = 0;
        if (pf) {
            const f32x4* nep = (const f32x4*)(ea + (size_t)(gn * 16 + ln) * 8);
            ean0 = nep[0]; ean1 = nep[1];
            const f32x4* nxp = (const f32x4*)(x + (size_t)s_nx * 16);
            xn0 = nxp[0]; xn1 = nxp[1]; xn2 = nxp[2]; xn3 = nxp[3];
            const int gnn = gn + ESTRIDE;
            if (gnn < NG) s_nx2 = ei[gnn * 16 + ln];
        }
        // my edge's dst (16 distinct, replicated across kg quartets)
        const int d_l = ei[E_EDGES + g16 + ln];
        if (kg == 0) atomicAdd(&cnt_u[d_l], 1u);

        // ---- h = relu(ea@W1 + b1) via 2 MFMAs (kg==0 lanes carry the B-frag)
        bf16x8 eb;
        if (kg == 0) {
            eb[0]=(__bf16)eac0[0]; eb[1]=(__bf16)eac0[1]; eb[2]=(__bf16)eac0[2]; eb[3]=(__bf16)eac0[3];
            eb[4]=(__bf16)eac1[0]; eb[5]=(__bf16)eac1[1]; eb[6]=(__bf16)eac1[2]; eb[7]=(__bf16)eac1[3];
        } else {
            eb[0]=zb; eb[1]=zb; eb[2]=zb; eb[3]=zb; eb[4]=zb; eb[5]=zb; eb[6]=zb; eb[7]=zb;
        }
        const f32x4 hA0 = __builtin_amdgcn_mfma_f32_16x16x32_bf16(aw0, eb, z4, 0, 0, 0);
        const f32x4 hA1 = __builtin_amdgcn_mfma_f32_16x16x32_bf16(aw1, eb, z4, 0, 0, 0);

        float h[8];
#pragma unroll
        for (int r = 0; r < 4; ++r) {
            h[r]     = fmaxf(hA0[r] + blo4[r], 0.f);
            h[4 + r] = fmaxf(hA1[r] + bhi4[r], 0.f);
        }

        float xr[16];
        xr[0]=xc0[0]; xr[1]=xc0[1]; xr[2]=xc0[2]; xr[3]=xc0[3];
        xr[4]=xc1[0]; xr[5]=xc1[1]; xr[6]=xc1[2]; xr[7]=xc1[3];
        xr[8]=xc2[0]; xr[9]=xc2[1]; xr[10]=xc2[2]; xr[11]=xc2[3];
        xr[12]=xc3[0]; xr[13]=xc3[1]; xr[14]=xc3[2]; xr[15]=xc3[3];

        f32x4 acc0 = z4, acc1 = z4;

#pragma unroll
        for (int kt = 0; kt < 16; ++kt) {
            const float xv = xr[kt];
            bf16x8 a;                         // B-operand: A'[e=ln][k=kap]
#pragma unroll
            for (int j = 0; j < 8; ++j) a[j] = (__bf16)(xv * h[j]);
            const bf16x8 bf0 = *(const bf16x8*)(&w2l[(kt * 2 + 0) * 512 + lane * 8]);
            const bf16x8 bf1 = *(const bf16x8*)(&w2l[(kt * 2 + 1) * 512 + lane * 8]);
            acc0 = __builtin_amdgcn_mfma_f32_16x16x32_bf16(bf0, a, acc0, 0, 0, 0);
            acc1 = __builtin_amdgcn_mfma_f32_16x16x32_bf16(bf1, a, acc1, 0, 0, 0);
        }
        { // 17th K-tile folds b2: B[k=kap][e] = x[e][kap] (kap<16), else 0
            const f32x4 xs = (kg == 0) ? xc0 : ((kg == 1) ? xc1 : ((kg == 2) ? xc2 : xc3));
            bf16x8 a;
            a[0]=(__bf16)xs[0]; a[1]=(__bf16)xs[1]; a[2]=(__bf16)xs[2]; a[3]=(__bf16)xs[3];
            a[4]=zb; a[5]=zb; a[6]=zb; a[7]=zb;
            const bf16x8 bf0 = *(const bf16x8*)(&w2l[(16 * 2 + 0) * 512 + lane * 8]);
            const bf16x8 bf1 = *(const bf16x8*)(&w2l[(16 * 2 + 1) * 512 + lane * 8]);
            acc0 = __builtin_amdgcn_mfma_f32_16x16x32_bf16(bf0, a, acc0, 0, 0, 0);
            acc1 = __builtin_amdgcn_mfma_f32_16x16x32_bf16(bf1, a, acc1, 0, 0, 0);
        }

        // ---- scatter: lane owns edge ln; acc0[r] -> o=kg*4+r, acc1[r] -> o=16+kg*4+r
        {
            float* base = agg + (size_t)d_l * 32 + kg * 4;
            atomicAdd(base + 0,  acc0[0]);
            atomicAdd(base + 1,  acc0[1]);
            atomicAdd(base + 2,  acc0[2]);
            atomicAdd(base + 3,  acc0[3]);
            atomicAdd(base + 16, acc1[0]);
            atomicAdd(base + 17, acc1[1]);
            atomicAdd(base + 18, acc1[2]);
            atomicAdd(base + 19, acc1[3]);
        }

        if (!pf) break;
        g = gn;
        eac0 = ean0; eac1 = ean1;
        xc0 = xn0; xc1 = xn1; xc2 = xn2; xc3 = xn3;
        s_nx = s_nx2;
    }
}

// ---------------------------------------------------------------------------
// K_node: fused  a = relu(agg/cnt + x@root + bias)  then  out = a@Wlin + blin
// ---------------------------------------------------------------------------
__global__ void __launch_bounds__(256) k_node(const float* __restrict__ agg,
                                              const uint* __restrict__ cnt_u,
                                              const float* __restrict__ x,
                                              const float* __restrict__ root,
                                              const float* __restrict__ bias,
                                              const float* __restrict__ Wlin,
                                              const float* __restrict__ blin,
                                              float* __restrict__ out) {
    __shared__ float al[256];
    const int n0 = blockIdx.x * 8;
    const int t = threadIdx.x;
    const int n = n0 + (t >> 5), h = t & 31;
    float a = 0.0f;
    if (n < N_NODES) {
        const float c = (float)cnt_u[n];
        float s = agg[n * 32 + h] / fmaxf(c, 1.0f) + bias[h];
        const f32x4* xp = (const f32x4*)(x + (size_t)n * 16);
        const f32x4 x0 = xp[0], x1 = xp[1], x2 = xp[2], x3 = xp[3];
        float xv[16];
        xv[0]=x0[0]; xv[1]=x0[1]; xv[2]=x0[2]; xv[3]=x0[3];
        xv[4]=x1[0]; xv[5]=x1[1]; xv[6]=x1[2]; xv[7]=x1[3];
        xv[8]=x2[0]; xv[9]=x2[1]; xv[10]=x2[2]; xv[11]=x2[3];
        xv[12]=x3[0]; xv[13]=x3[1]; xv[14]=x3[2]; xv[15]=x3[3];
#pragma unroll
        for (int i = 0; i < 16; ++i) s += xv[i] * root[i * 32 + h];
        a = fmaxf(s, 0.0f);
    }
    al[t] = a;
    __syncthreads();
    if (t < 128) {
        const int nj = n0 + (t >> 4), j = t & 15;
        if (nj < N_NODES) {
            float s = blin[j];
#pragma unroll
            for (int h2 = 0; h2 < 32; ++h2) s += al[(t >> 4) * 32 + h2] * Wlin[h2 * 16 + j];
            out[nj * 16 + j] = s;
        }
    }
}

// ---------------------------------------------------------------------------
extern "C" void kernel_launch(void* const* d_in, const int* in_sizes, int n_in,
                              void* d_out, int out_size, void* d_ws, size_t ws_size,
                              hipStream_t stream) {
    const float* x    = (const float*)d_in[0];
    const float* ea   = (const float*)d_in[1];
    const float* W1   = (const float*)d_in[2];
    const float* b1   = (const float*)d_in[3];
    const float* W2   = (const float*)d_in[4];
    const float* b2   = (const float*)d_in[5];
    const float* root = (const float*)d_in[6];
    const float* bias = (const float*)d_in[7];
    const float* Wlin = (const float*)d_in[8];
    const float* blin = (const float*)d_in[9];
    const int*   ei   = (const int*)d_in[10];
    float* out = (float*)d_out;

    char* ws = (char*)d_ws;
    float*  agg    = (float*)(ws + 0);           // 3,200,000
    uint*   cnt_u  = (uint*)(ws + 3200000);      //   100,000
    ushort* packed = (ushort*)(ws + 3300000);    //    36,864

    hipMemsetAsync(d_ws, 0, 3300000, stream);    // agg + cnt_u

    k_pack<<<(NPACK + 255) / 256, 256, 0, stream>>>(W2, b2, W1, packed);
    k_edge<<<EBLOCKS, 256, 0, stream>>>(ea, x, ei, packed, b1, agg, cnt_u);
    k_node<<<3125, 256, 0, stream>>>(agg, cnt_u, x, root, bias, Wlin, blin, out);
}

// Round 10
// 87.099 us; speedup vs baseline: 2.3626x; 2.3626x over previous
//
#include <hip/hip_runtime.h>
#include <cstdint>

#define E_EDGES 400000
#define N_NODES 25000
#define NU      12500          // units of 32 edges (2 MFMA groups of 16)
#define NPACK   18432          // ushorts: 17 K-tiles (17408) + 2 W1^T A-frags (1024)
#define EBLOCKS 1024           // exactly 4 blocks/CU (34.8KB LDS each)
#define ESTRIDE (EBLOCKS*4)    // 4096 waves; ~3 units each

typedef float  f32x4  __attribute__((ext_vector_type(4)));
typedef __bf16 bf16x8 __attribute__((ext_vector_type(8)));

static __device__ __forceinline__ ushort f2bf(float f) {
    union { __bf16 b; ushort u; } c; c.b = (__bf16)f; return c.u;
}

// ---------------------------------------------------------------------------
// K_pack: W2(+b2 17th tile) -> MFMA B-frag order with kap remap; W1^T A-frags.
// kap(kg,j) = j<4 ? 4kg+j : 16+4kg+(j-4)   (matches h-MFMA C layout)
// ---------------------------------------------------------------------------
__global__ void __launch_bounds__(256) k_pack(const float* __restrict__ W2,
                                              const float* __restrict__ b2,
                                              const float* __restrict__ W1,
                                              ushort* __restrict__ packed) {
    int t = blockIdx.x * 256 + threadIdx.x;
    if (t >= NPACK) return;
    float v = 0.0f;
    if (t < 17408) {
        int j  = t & 7;
        int ln = (t >> 3) & 15;
        int kg = (t >> 7) & 3;
        int nt = (t >> 9) & 1;
        int kt = t >> 10;
        int kap = (j < 4) ? (kg * 4 + j) : (16 + kg * 4 + (j - 4));
        if (kt < 16)       v = W2[kap * 512 + kt * 32 + nt * 16 + ln];
        else if (kap < 16) v = b2[kap * 32 + nt * 16 + ln];
    } else {
        int idx  = t - 17408;
        int half = idx >> 9;
        int lane = (idx >> 3) & 63;
        int j    = idx & 7;
        int kg = lane >> 4, ln = lane & 15;
        if (kg == 0) v = W1[j * 32 + half * 16 + ln];  // A[m=ln(+16*half)][k=j]
    }
    packed[t] = f2bf(v);
}

// ---------------------------------------------------------------------------
// K_edge: 2 groups (32 edges) per wave iteration; B-fragments read ONCE from
// LDS and shared by both groups (17 ds_read/group); 4 independent acc chains.
// Full-body prefetch: ei 2 units ahead, ea/x 1 unit ahead.
// Coalesced row-aligned scatter (r5 shape: 16 lanes cover one dst row).
// Grid: 1024 blocks = 4/CU resident; grid-stride over 12500 units.
// ---------------------------------------------------------------------------
__global__ void __launch_bounds__(256) k_edge(const float* __restrict__ ea,
                                              const float* __restrict__ x,
                                              const int* __restrict__ ei,
                                              const ushort* __restrict__ packed,
                                              const float* __restrict__ b1,
                                              float* __restrict__ agg,
                                              uint* __restrict__ cnt_u) {
    __shared__ alignas(16) ushort w2l[17408];
    {
        const uint4* s = (const uint4*)packed;
        uint4* d = (uint4*)w2l;
        for (int i = threadIdx.x; i < 2176; i += 256) d[i] = s[i];
    }
    __syncthreads();

    const int lane = threadIdx.x & 63;
    const int ln = lane & 15;
    const int kg = lane >> 4;
    const int wid = blockIdx.x * 4 + (threadIdx.x >> 6);

    // loop-invariant register state
    const bf16x8 aw0 = *(const bf16x8*)(packed + 17408 + (size_t)lane * 8);
    const bf16x8 aw1 = *(const bf16x8*)(packed + 17408 + 512 + (size_t)lane * 8);
    const f32x4 blo4 = *(const f32x4*)(b1 + 4 * kg);
    const f32x4 bhi4 = *(const f32x4*)(b1 + 16 + 4 * kg);

    const f32x4 z4 = {0.f, 0.f, 0.f, 0.f};
    const __bf16 zb = (__bf16)0.0f;

    // ---- pipeline state (unit u = 32 edges: group A = first 16, B = last 16)
    int g = wid;                            // wid < 4096 <= NU
    f32x4 eaA0, eaA1, eaB0, eaB1;
    f32x4 xA0, xA1, xA2, xA3, xB0, xB1, xB2, xB3;
    int sA_nx = 0, sB_nx = 0;
    {
        const int sA = ei[g * 32 + ln];
        const int sB = ei[g * 32 + 16 + ln];
        const f32x4* epA = (const f32x4*)(ea + (size_t)(g * 32 + ln) * 8);
        eaA0 = epA[0]; eaA1 = epA[1];
        const f32x4* epB = (const f32x4*)(ea + (size_t)(g * 32 + 16 + ln) * 8);
        eaB0 = epB[0]; eaB1 = epB[1];
        const f32x4* xpA = (const f32x4*)(x + (size_t)sA * 16);
        xA0 = xpA[0]; xA1 = xpA[1]; xA2 = xpA[2]; xA3 = xpA[3];
        const f32x4* xpB = (const f32x4*)(x + (size_t)sB * 16);
        xB0 = xpB[0]; xB1 = xpB[1]; xB2 = xpB[2]; xB3 = xpB[3];
        const int g1 = g + ESTRIDE;
        if (g1 < NU) {
            sA_nx = ei[g1 * 32 + ln];
            sB_nx = ei[g1 * 32 + 16 + ln];
        }
    }

    while (true) {
        const int gn = g + ESTRIDE;
        const bool pf = gn < NU;

        // ---- issue next unit's ea + x, and ei srcs two units ahead
        f32x4 neaA0 = z4, neaA1 = z4, neaB0 = z4, neaB1 = z4;
        f32x4 nxA0 = z4, nxA1 = z4, nxA2 = z4, nxA3 = z4;
        f32x4 nxB0 = z4, nxB1 = z4, nxB2 = z4, nxB3 = z4;
        int sA_nn = 0, sB_nn = 0;
        if (pf) {
            const f32x4* nepA = (const f32x4*)(ea + (size_t)(gn * 32 + ln) * 8);
            neaA0 = nepA[0]; neaA1 = nepA[1];
            const f32x4* nepB = (const f32x4*)(ea + (size_t)(gn * 32 + 16 + ln) * 8);
            neaB0 = nepB[0]; neaB1 = nepB[1];
            const f32x4* nxpA = (const f32x4*)(x + (size_t)sA_nx * 16);
            nxA0 = nxpA[0]; nxA1 = nxpA[1]; nxA2 = nxpA[2]; nxA3 = nxpA[3];
            const f32x4* nxpB = (const f32x4*)(x + (size_t)sB_nx * 16);
            nxB0 = nxpB[0]; nxB1 = nxpB[1]; nxB2 = nxpB[2]; nxB3 = nxpB[3];
            const int gnn = gn + ESTRIDE;
            if (gnn < NU) {
                sA_nn = ei[gnn * 32 + ln];
                sB_nn = ei[gnn * 32 + 16 + ln];
            }
        }
        const int4 d4A = *(const int4*)(ei + E_EDGES + g * 32 + kg * 4);
        const int4 d4B = *(const int4*)(ei + E_EDGES + g * 32 + 16 + kg * 4);

        // ---- cnt histogram: lanes ln<4 cover all 32 edges via kg quartets
        if (ln < 4) {
            const int dA = (ln == 0) ? d4A.x : ((ln == 1) ? d4A.y : ((ln == 2) ? d4A.z : d4A.w));
            const int dB = (ln == 0) ? d4B.x : ((ln == 1) ? d4B.y : ((ln == 2) ? d4B.z : d4B.w));
            atomicAdd(&cnt_u[dA], 1u);
            atomicAdd(&cnt_u[dB], 1u);
        }

        // ---- h = relu(ea@W1 + b1) for both groups (kg==0 lanes carry B-frag)
        bf16x8 ebA, ebB;
        if (kg == 0) {
            ebA[0]=(__bf16)eaA0[0]; ebA[1]=(__bf16)eaA0[1]; ebA[2]=(__bf16)eaA0[2]; ebA[3]=(__bf16)eaA0[3];
            ebA[4]=(__bf16)eaA1[0]; ebA[5]=(__bf16)eaA1[1]; ebA[6]=(__bf16)eaA1[2]; ebA[7]=(__bf16)eaA1[3];
            ebB[0]=(__bf16)eaB0[0]; ebB[1]=(__bf16)eaB0[1]; ebB[2]=(__bf16)eaB0[2]; ebB[3]=(__bf16)eaB0[3];
            ebB[4]=(__bf16)eaB1[0]; ebB[5]=(__bf16)eaB1[1]; ebB[6]=(__bf16)eaB1[2]; ebB[7]=(__bf16)eaB1[3];
        } else {
            ebA[0]=zb; ebA[1]=zb; ebA[2]=zb; ebA[3]=zb; ebA[4]=zb; ebA[5]=zb; ebA[6]=zb; ebA[7]=zb;
            ebB = ebA;
        }
        const f32x4 hA0 = __builtin_amdgcn_mfma_f32_16x16x32_bf16(aw0, ebA, z4, 0, 0, 0);
        const f32x4 hA1 = __builtin_amdgcn_mfma_f32_16x16x32_bf16(aw1, ebA, z4, 0, 0, 0);
        const f32x4 hB0 = __builtin_amdgcn_mfma_f32_16x16x32_bf16(aw0, ebB, z4, 0, 0, 0);
        const f32x4 hB1 = __builtin_amdgcn_mfma_f32_16x16x32_bf16(aw1, ebB, z4, 0, 0, 0);

        float hA[8], hB[8];
#pragma unroll
        for (int r = 0; r < 4; ++r) {
            hA[r]     = fmaxf(hA0[r] + blo4[r], 0.f);
            hA[4 + r] = fmaxf(hA1[r] + bhi4[r], 0.f);
            hB[r]     = fmaxf(hB0[r] + blo4[r], 0.f);
            hB[4 + r] = fmaxf(hB1[r] + bhi4[r], 0.f);
        }

        float xrA[16], xrB[16];
        xrA[0]=xA0[0]; xrA[1]=xA0[1]; xrA[2]=xA0[2]; xrA[3]=xA0[3];
        xrA[4]=xA1[0]; xrA[5]=xA1[1]; xrA[6]=xA1[2]; xrA[7]=xA1[3];
        xrA[8]=xA2[0]; xrA[9]=xA2[1]; xrA[10]=xA2[2]; xrA[11]=xA2[3];
        xrA[12]=xA3[0]; xrA[13]=xA3[1]; xrA[14]=xA3[2]; xrA[15]=xA3[3];
        xrB[0]=xB0[0]; xrB[1]=xB0[1]; xrB[2]=xB0[2]; xrB[3]=xB0[3];
        xrB[4]=xB1[0]; xrB[5]=xB1[1]; xrB[6]=xB1[2]; xrB[7]=xB1[3];
        xrB[8]=xB2[0]; xrB[9]=xB2[1]; xrB[10]=xB2[2]; xrB[11]=xB2[3];
        xrB[12]=xB3[0]; xrB[13]=xB3[1]; xrB[14]=xB3[2]; xrB[15]=xB3[3];

        f32x4 accA0 = z4, accA1 = z4, accB0 = z4, accB1 = z4;

#pragma unroll
        for (int kt = 0; kt < 16; ++kt) {
            const bf16x8 bf0 = *(const bf16x8*)(&w2l[(kt * 2 + 0) * 512 + lane * 8]);
            const bf16x8 bf1 = *(const bf16x8*)(&w2l[(kt * 2 + 1) * 512 + lane * 8]);
            const float xvA = xrA[kt], xvB = xrB[kt];
            bf16x8 aA, aB;
#pragma unroll
            for (int j = 0; j < 8; ++j) {
                aA[j] = (__bf16)(xvA * hA[j]);
                aB[j] = (__bf16)(xvB * hB[j]);
            }
            accA0 = __builtin_amdgcn_mfma_f32_16x16x32_bf16(aA, bf0, accA0, 0, 0, 0);
            accB0 = __builtin_amdgcn_mfma_f32_16x16x32_bf16(aB, bf0, accB0, 0, 0, 0);
            accA1 = __builtin_amdgcn_mfma_f32_16x16x32_bf16(aA, bf1, accA1, 0, 0, 0);
            accB1 = __builtin_amdgcn_mfma_f32_16x16x32_bf16(aB, bf1, accB1, 0, 0, 0);
        }
        { // 17th K-tile folds b2: a[j<4] = x[4kg+j], a[j>=4] = 0
            const f32x4 xsA = (kg == 0) ? xA0 : ((kg == 1) ? xA1 : ((kg == 2) ? xA2 : xA3));
            const f32x4 xsB = (kg == 0) ? xB0 : ((kg == 1) ? xB1 : ((kg == 2) ? xB2 : xB3));
            bf16x8 aA, aB;
            aA[0]=(__bf16)xsA[0]; aA[1]=(__bf16)xsA[1]; aA[2]=(__bf16)xsA[2]; aA[3]=(__bf16)xsA[3];
            aA[4]=zb; aA[5]=zb; aA[6]=zb; aA[7]=zb;
            aB[0]=(__bf16)xsB[0]; aB[1]=(__bf16)xsB[1]; aB[2]=(__bf16)xsB[2]; aB[3]=(__bf16)xsB[3];
            aB[4]=zb; aB[5]=zb; aB[6]=zb; aB[7]=zb;
            const bf16x8 bf0 = *(const bf16x8*)(&w2l[(16 * 2 + 0) * 512 + lane * 8]);
            const bf16x8 bf1 = *(const bf16x8*)(&w2l[(16 * 2 + 1) * 512 + lane * 8]);
            accA0 = __builtin_amdgcn_mfma_f32_16x16x32_bf16(aA, bf0, accA0, 0, 0, 0);
            accB0 = __builtin_amdgcn_mfma_f32_16x16x32_bf16(aB, bf0, accB0, 0, 0, 0);
            accA1 = __builtin_amdgcn_mfma_f32_16x16x32_bf16(aA, bf1, accA1, 0, 0, 0);
            accB1 = __builtin_amdgcn_mfma_f32_16x16x32_bf16(aB, bf1, accB1, 0, 0, 0);
        }

        // ---- coalesced scatter: 16 lanes of a kg-quartet cover one dst row
        atomicAdd(&agg[d4A.x * 32 + ln],      accA0[0]);
        atomicAdd(&agg[d4A.y * 32 + ln],      accA0[1]);
        atomicAdd(&agg[d4A.z * 32 + ln],      accA0[2]);
        atomicAdd(&agg[d4A.w * 32 + ln],      accA0[3]);
        atomicAdd(&agg[d4A.x * 32 + 16 + ln], accA1[0]);
        atomicAdd(&agg[d4A.y * 32 + 16 + ln], accA1[1]);
        atomicAdd(&agg[d4A.z * 32 + 16 + ln], accA1[2]);
        atomicAdd(&agg[d4A.w * 32 + 16 + ln], accA1[3]);
        atomicAdd(&agg[d4B.x * 32 + ln],      accB0[0]);
        atomicAdd(&agg[d4B.y * 32 + ln],      accB0[1]);
        atomicAdd(&agg[d4B.z * 32 + ln],      accB0[2]);
        atomicAdd(&agg[d4B.w * 32 + ln],      accB0[3]);
        atomicAdd(&agg[d4B.x * 32 + 16 + ln], accB1[0]);
        atomicAdd(&agg[d4B.y * 32 + 16 + ln], accB1[1]);
        atomicAdd(&agg[d4B.z * 32 + 16 + ln], accB1[2]);
        atomicAdd(&agg[d4B.w * 32 + 16 + ln], accB1[3]);

        if (!pf) break;
        g = gn;
        eaA0 = neaA0; eaA1 = neaA1; eaB0 = neaB0; eaB1 = neaB1;
        xA0 = nxA0; xA1 = nxA1; xA2 = nxA2; xA3 = nxA3;
        xB0 = nxB0; xB1 = nxB1; xB2 = nxB2; xB3 = nxB3;
        sA_nx = sA_nn; sB_nx = sB_nn;
    }
}

// ---------------------------------------------------------------------------
// K_node: fused  a = relu(agg/cnt + x@root + bias)  then  out = a@Wlin + blin
// ---------------------------------------------------------------------------
__global__ void __launch_bounds__(256) k_node(const float* __restrict__ agg,
                                              const uint* __restrict__ cnt_u,
                                              const float* __restrict__ x,
                                              const float* __restrict__ root,
                                              const float* __restrict__ bias,
                                              const float* __restrict__ Wlin,
                                              const float* __restrict__ blin,
                                              float* __restrict__ out) {
    __shared__ float al[256];
    const int n0 = blockIdx.x * 8;
    const int t = threadIdx.x;
    const int n = n0 + (t >> 5), h = t & 31;
    float a = 0.0f;
    if (n < N_NODES) {
        const float c = (float)cnt_u[n];
        float s = agg[n * 32 + h] / fmaxf(c, 1.0f) + bias[h];
        const f32x4* xp = (const f32x4*)(x + (size_t)n * 16);
        const f32x4 x0 = xp[0], x1 = xp[1], x2 = xp[2], x3 = xp[3];
        float xv[16];
        xv[0]=x0[0]; xv[1]=x0[1]; xv[2]=x0[2]; xv[3]=x0[3];
        xv[4]=x1[0]; xv[5]=x1[1]; xv[6]=x1[2]; xv[7]=x1[3];
        xv[8]=x2[0]; xv[9]=x2[1]; xv[10]=x2[2]; xv[11]=x2[3];
        xv[12]=x3[0]; xv[13]=x3[1]; xv[14]=x3[2]; xv[15]=x3[3];
#pragma unroll
        for (int i = 0; i < 16; ++i) s += xv[i] * root[i * 32 + h];
        a = fmaxf(s, 0.0f);
    }
    al[t] = a;
    __syncthreads();
    if (t < 128) {
        const int nj = n0 + (t >> 4), j = t & 15;
        if (nj < N_NODES) {
            float s = blin[j];
#pragma unroll
            for (int h2 = 0; h2 < 32; ++h2) s += al[(t >> 4) * 32 + h2] * Wlin[h2 * 16 + j];
            out[nj * 16 + j] = s;
        }
    }
}

// ---------------------------------------------------------------------------
extern "C" void kernel_launch(void* const* d_in, const int* in_sizes, int n_in,
                              void* d_out, int out_size, void* d_ws, size_t ws_size,
                              hipStream_t stream) {
    const float* x    = (const float*)d_in[0];
    const float* ea   = (const float*)d_in[1];
    const float* W1   = (const float*)d_in[2];
    const float* b1   = (const float*)d_in[3];
    const float* W2   = (const float*)d_in[4];
    const float* b2   = (const float*)d_in[5];
    const float* root = (const float*)d_in[6];
    const float* bias = (const float*)d_in[7];
    const float* Wlin = (const float*)d_in[8];
    const float* blin = (const float*)d_in[9];
    const int*   ei   = (const int*)d_in[10];
    float* out = (float*)d_out;

    char* ws = (char*)d_ws;
    float*  agg    = (float*)(ws + 0);           // 3,200,000
    uint*   cnt_u  = (uint*)(ws + 3200000);      //   100,000
    ushort* packed = (ushort*)(ws + 3300000);    //    36,864

    hipMemsetAsync(d_ws, 0, 3300000, stream);    // agg + cnt_u

    k_pack<<<(NPACK + 255) / 256, 256, 0, stream>>>(W2, b2, W1, packed);
    k_edge<<<EBLOCKS, 256, 0, stream>>>(ea, x, ei, packed, b1, agg, cnt_u);
    k_node<<<3125, 256, 0, stream>>>(agg, cnt_u, x, root, bias, Wlin, blin, out);
}

// Round 11
// 83.845 us; speedup vs baseline: 2.4543x; 1.0388x over previous
//
#include <hip/hip_runtime.h>
#include <cstdint>

#define E_EDGES 400000
#define N_NODES 25000
#define NG      25000          // groups of 16 edges
#define NPACK   18432          // ushorts: 17 K-tiles (17408) + 2 W1^T A-frags (1024)
#define EBLOCKS 1024           // 4 blocks/CU (34.8KB LDS each)
#define ESTRIDE (EBLOCKS*4)    // 4096 waves; ~6 groups each

typedef float  f32x4  __attribute__((ext_vector_type(4)));
typedef __bf16 bf16x8 __attribute__((ext_vector_type(8)));

static __device__ __forceinline__ ushort f2bf(float f) {
    union { __bf16 b; ushort u; } c; c.b = (__bf16)f; return c.u;
}

// ---------------------------------------------------------------------------
// K_pre: zero agg+cnt (grid-stride) AND pack W2(+b2)/W1^T frags. One dispatch.
// kap(kg,j) = j<4 ? 4kg+j : 16+4kg+(j-4)   (matches h-MFMA C layout)
// ---------------------------------------------------------------------------
__global__ void __launch_bounds__(256) k_pre(const float* __restrict__ W2,
                                             const float* __restrict__ b2,
                                             const float* __restrict__ W1,
                                             ushort* __restrict__ packed,
                                             uint* __restrict__ zbase) {
    const int t = blockIdx.x * 256 + threadIdx.x;
    // zero 825,000 uints (agg 800,000 + cnt 25,000)
    for (int i = t; i < 825000; i += EBLOCKS * 256) zbase[i] = 0u;
    if (t >= NPACK) return;
    float v = 0.0f;
    if (t < 17408) {
        int j  = t & 7;
        int ln = (t >> 3) & 15;
        int kg = (t >> 7) & 3;
        int nt = (t >> 9) & 1;
        int kt = t >> 10;
        int kap = (j < 4) ? (kg * 4 + j) : (16 + kg * 4 + (j - 4));
        if (kt < 16)       v = W2[kap * 512 + kt * 32 + nt * 16 + ln];
        else if (kap < 16) v = b2[kap * 32 + nt * 16 + ln];
    } else {
        int idx  = t - 17408;
        int half = idx >> 9;
        int lane = (idx >> 3) & 63;
        int j    = idx & 7;
        int kg = lane >> 4, ln = lane & 15;
        if (kg == 0) v = W1[j * 32 + half * 16 + ln];  // A[m=ln(+16*half)][k=j]
    }
    packed[t] = f2bf(v);
}

// ---------------------------------------------------------------------------
// K_edge: 1 group/iter, two-level pipeline (ei 2 bodies ahead, ea/x 1 body
// ahead), W2' in LDS, h via MFMA, row-aligned coalesced atomics, cnt inline.
// No min-waves hint; register state kept lean (<128 VGPR) for 4 waves/SIMD.
// ---------------------------------------------------------------------------
__global__ void __launch_bounds__(256) k_edge(const float* __restrict__ ea,
                                              const float* __restrict__ x,
                                              const int* __restrict__ ei,
                                              const ushort* __restrict__ packed,
                                              const float* __restrict__ b1,
                                              float* __restrict__ agg,
                                              uint* __restrict__ cnt_u) {
    __shared__ alignas(16) ushort w2l[17408];
    {
        const uint4* s = (const uint4*)packed;
        uint4* d = (uint4*)w2l;
        for (int i = threadIdx.x; i < 2176; i += 256) d[i] = s[i];
    }
    __syncthreads();

    const int lane = threadIdx.x & 63;
    const int ln = lane & 15;
    const int kg = lane >> 4;
    const int wid = blockIdx.x * 4 + (threadIdx.x >> 6);

    // loop-invariant register state
    const bf16x8 aw0 = *(const bf16x8*)(packed + 17408 + (size_t)lane * 8);
    const bf16x8 aw1 = *(const bf16x8*)(packed + 17408 + 512 + (size_t)lane * 8);
    const f32x4 blo4 = *(const f32x4*)(b1 + 4 * kg);
    const f32x4 bhi4 = *(const f32x4*)(b1 + 16 + 4 * kg);

    const f32x4 z4 = {0.f, 0.f, 0.f, 0.f};
    const __bf16 zb = (__bf16)0.0f;

    // ---- pipeline state
    int g = wid;                            // wid < 4096 <= NG
    f32x4 eac0, eac1, xc0, xc1, xc2, xc3;
    int s_nx = 0;
    {
        const int s0 = ei[g * 16 + ln];
        const f32x4* ep = (const f32x4*)(ea + (size_t)(g * 16 + ln) * 8);
        eac0 = ep[0]; eac1 = ep[1];
        const f32x4* xp = (const f32x4*)(x + (size_t)s0 * 16);
        xc0 = xp[0]; xc1 = xp[1]; xc2 = xp[2]; xc3 = xp[3];
        const int g1 = g + ESTRIDE;
        if (g1 < NG) s_nx = ei[g1 * 16 + ln];
    }

    while (true) {
        const int gn = g + ESTRIDE;
        const bool pf = gn < NG;
        const int g16 = g * 16;

        // ---- issue next body's ea + x, and ei two bodies ahead
        f32x4 ean0 = z4, ean1 = z4, xn0 = z4, xn1 = z4, xn2 = z4, xn3 = z4;
        int s_nx2 = 0;
        if (pf) {
            const f32x4* nep = (const f32x4*)(ea + (size_t)(gn * 16 + ln) * 8);
            ean0 = nep[0]; ean1 = nep[1];
            const f32x4* nxp = (const f32x4*)(x + (size_t)s_nx * 16);
            xn0 = nxp[0]; xn1 = nxp[1]; xn2 = nxp[2]; xn3 = nxp[3];
            const int gnn = gn + ESTRIDE;
            if (gnn < NG) s_nx2 = ei[gnn * 16 + ln];
        }
        const int4 d4 = *(const int4*)(ei + E_EDGES + g16 + kg * 4);

        // ---- cnt histogram: lanes ln<4 of each kg quartet cover 16 edges
        if (ln < 4) {
            const int dsel = (ln == 0) ? d4.x : ((ln == 1) ? d4.y : ((ln == 2) ? d4.z : d4.w));
            atomicAdd(&cnt_u[dsel], 1u);
        }

        // ---- h = relu(ea@W1 + b1) via 2 MFMAs (kg==0 lanes carry the B-frag)
        bf16x8 eb;
        if (kg == 0) {
            eb[0]=(__bf16)eac0[0]; eb[1]=(__bf16)eac0[1]; eb[2]=(__bf16)eac0[2]; eb[3]=(__bf16)eac0[3];
            eb[4]=(__bf16)eac1[0]; eb[5]=(__bf16)eac1[1]; eb[6]=(__bf16)eac1[2]; eb[7]=(__bf16)eac1[3];
        } else {
            eb[0]=zb; eb[1]=zb; eb[2]=zb; eb[3]=zb; eb[4]=zb; eb[5]=zb; eb[6]=zb; eb[7]=zb;
        }
        const f32x4 hA0 = __builtin_amdgcn_mfma_f32_16x16x32_bf16(aw0, eb, z4, 0, 0, 0);
        const f32x4 hA1 = __builtin_amdgcn_mfma_f32_16x16x32_bf16(aw1, eb, z4, 0, 0, 0);

        float h[8];
#pragma unroll
        for (int r = 0; r < 4; ++r) {
            h[r]     = fmaxf(hA0[r] + blo4[r], 0.f);
            h[4 + r] = fmaxf(hA1[r] + bhi4[r], 0.f);
        }

        f32x4 acc0 = z4, acc1 = z4;

#pragma unroll
        for (int kt = 0; kt < 16; ++kt) {
            // compile-time select of the x component (no register array copy)
            const f32x4 xqs = (kt < 4) ? xc0 : ((kt < 8) ? xc1 : ((kt < 12) ? xc2 : xc3));
            const float xv = xqs[kt & 3];
            bf16x8 a;
#pragma unroll
            for (int j = 0; j < 8; ++j) a[j] = (__bf16)(xv * h[j]);
            const bf16x8 bf0 = *(const bf16x8*)(&w2l[(kt * 2 + 0) * 512 + lane * 8]);
            const bf16x8 bf1 = *(const bf16x8*)(&w2l[(kt * 2 + 1) * 512 + lane * 8]);
            acc0 = __builtin_amdgcn_mfma_f32_16x16x32_bf16(a, bf0, acc0, 0, 0, 0);
            acc1 = __builtin_amdgcn_mfma_f32_16x16x32_bf16(a, bf1, acc1, 0, 0, 0);
        }
        { // 17th K-tile folds b2: a[j<4] = x[4kg+j], a[j>=4] = 0
            const f32x4 xs = (kg == 0) ? xc0 : ((kg == 1) ? xc1 : ((kg == 2) ? xc2 : xc3));
            bf16x8 a;
            a[0]=(__bf16)xs[0]; a[1]=(__bf16)xs[1]; a[2]=(__bf16)xs[2]; a[3]=(__bf16)xs[3];
            a[4]=zb; a[5]=zb; a[6]=zb; a[7]=zb;
            const bf16x8 bf0 = *(const bf16x8*)(&w2l[(16 * 2 + 0) * 512 + lane * 8]);
            const bf16x8 bf1 = *(const bf16x8*)(&w2l[(16 * 2 + 1) * 512 + lane * 8]);
            acc0 = __builtin_amdgcn_mfma_f32_16x16x32_bf16(a, bf0, acc0, 0, 0, 0);
            acc1 = __builtin_amdgcn_mfma_f32_16x16x32_bf16(a, bf1, acc1, 0, 0, 0);
        }

        // ---- coalesced row-aligned scatter (16 lanes cover one dst row)
        atomicAdd(&agg[d4.x * 32 + ln],      acc0[0]);
        atomicAdd(&agg[d4.y * 32 + ln],      acc0[1]);
        atomicAdd(&agg[d4.z * 32 + ln],      acc0[2]);
        atomicAdd(&agg[d4.w * 32 + ln],      acc0[3]);
        atomicAdd(&agg[d4.x * 32 + 16 + ln], acc1[0]);
        atomicAdd(&agg[d4.y * 32 + 16 + ln], acc1[1]);
        atomicAdd(&agg[d4.z * 32 + 16 + ln], acc1[2]);
        atomicAdd(&agg[d4.w * 32 + 16 + ln], acc1[3]);

        if (!pf) break;
        g = gn;
        eac0 = ean0; eac1 = ean1;
        xc0 = xn0; xc1 = xn1; xc2 = xn2; xc3 = xn3;
        s_nx = s_nx2;
    }
}

// ---------------------------------------------------------------------------
// K_node: fused  a = relu(agg/cnt + x@root + bias)  then  out = a@Wlin + blin
// ---------------------------------------------------------------------------
__global__ void __launch_bounds__(256) k_node(const float* __restrict__ agg,
                                              const uint* __restrict__ cnt_u,
                                              const float* __restrict__ x,
                                              const float* __restrict__ root,
                                              const float* __restrict__ bias,
                                              const float* __restrict__ Wlin,
                                              const float* __restrict__ blin,
                                              float* __restrict__ out) {
    __shared__ float al[256];
    const int n0 = blockIdx.x * 8;
    const int t = threadIdx.x;
    const int n = n0 + (t >> 5), h = t & 31;
    float a = 0.0f;
    if (n < N_NODES) {
        const float c = (float)cnt_u[n];
        float s = agg[n * 32 + h] / fmaxf(c, 1.0f) + bias[h];
        const f32x4* xp = (const f32x4*)(x + (size_t)n * 16);
        const f32x4 x0 = xp[0], x1 = xp[1], x2 = xp[2], x3 = xp[3];
        float xv[16];
        xv[0]=x0[0]; xv[1]=x0[1]; xv[2]=x0[2]; xv[3]=x0[3];
        xv[4]=x1[0]; xv[5]=x1[1]; xv[6]=x1[2]; xv[7]=x1[3];
        xv[8]=x2[0]; xv[9]=x2[1]; xv[10]=x2[2]; xv[11]=x2[3];
        xv[12]=x3[0]; xv[13]=x3[1]; xv[14]=x3[2]; xv[15]=x3[3];
#pragma unroll
        for (int i = 0; i < 16; ++i) s += xv[i] * root[i * 32 + h];
        a = fmaxf(s, 0.0f);
    }
    al[t] = a;
    __syncthreads();
    if (t < 128) {
        const int nj = n0 + (t >> 4), j = t & 15;
        if (nj < N_NODES) {
            float s = blin[j];
#pragma unroll
            for (int h2 = 0; h2 < 32; ++h2) s += al[(t >> 4) * 32 + h2] * Wlin[h2 * 16 + j];
            out[nj * 16 + j] = s;
        }
    }
}

// ---------------------------------------------------------------------------
extern "C" void kernel_launch(void* const* d_in, const int* in_sizes, int n_in,
                              void* d_out, int out_size, void* d_ws, size_t ws_size,
                              hipStream_t stream) {
    const float* x    = (const float*)d_in[0];
    const float* ea   = (const float*)d_in[1];
    const float* W1   = (const float*)d_in[2];
    const float* b1   = (const float*)d_in[3];
    const float* W2   = (const float*)d_in[4];
    const float* b2   = (const float*)d_in[5];
    const float* root = (const float*)d_in[6];
    const float* bias = (const float*)d_in[7];
    const float* Wlin = (const float*)d_in[8];
    const float* blin = (const float*)d_in[9];
    const int*   ei   = (const int*)d_in[10];
    float* out = (float*)d_out;

    char* ws = (char*)d_ws;
    float*  agg    = (float*)(ws + 0);           // 3,200,000
    uint*   cnt_u  = (uint*)(ws + 3200000);      //   100,000
    ushort* packed = (ushort*)(ws + 3300000);    //    36,864

    k_pre<<<EBLOCKS, 256, 0, stream>>>(W2, b2, W1, packed, (uint*)ws);
    k_edge<<<EBLOCKS, 256, 0, stream>>>(ea, x, ei, packed, b1, agg, cnt_u);
    k_node<<<3125, 256, 0, stream>>>(agg, cnt_u, x, root, bias, Wlin, blin, out);
}